// Round 1
// baseline (128.732 us; speedup 1.0000x reference)
//
#include <hip/hip_runtime.h>

// Problem: B=1e6 rows, N=64 heads, D=3.
// u[b,n,k] = tanh( sum_d x[b,d]*W[n,k,d] + bias[n,k] )
// out_rho[b] = sum_n u[b,n,0]*c_rho[n]; out_p: k=1 w/ c_p; out_u: k=2 w/ c_u.
// d_out layout: [0..B) = out_rho, [B..2B) = out_p, [2B..3B) = out_u (f32).

#define NN   64
#define RPT  4     // rows per thread
#define BLK  256

__device__ __forceinline__ float fast_exp2(float x) {
#if __has_builtin(__builtin_amdgcn_exp2f)
    return __builtin_amdgcn_exp2f(x);
#else
    return exp2f(x);
#endif
}

__device__ __forceinline__ float fast_rcp(float x) {
#if __has_builtin(__builtin_amdgcn_rcpf)
    return __builtin_amdgcn_rcpf(x);
#else
    return 1.0f / x;
#endif
}

// tanh(x) = 1 - 2/(exp(2x)+1); exp(2x)=2^(x*2*log2(e)).
// Saturates correctly at +/-inf (rcp(inf)=0 -> 1; exp2(-inf)=0 -> -1).
__device__ __forceinline__ float fast_tanh(float x) {
    float e = fast_exp2(x * 2.8853900817779268f);
    float r = fast_rcp(e + 1.0f);
    return fmaf(-2.0f, r, 1.0f);
}

__global__ __launch_bounds__(BLK) void fused_tanh_heads(
    const float* __restrict__ x,     // [B,3]
    const float* __restrict__ W,     // [64,3,3]
    const float* __restrict__ bias,  // [64,3]
    const float* __restrict__ c_rho, // [64]
    const float* __restrict__ c_p,   // [64]
    const float* __restrict__ c_u,   // [64]
    float* __restrict__ out,         // [3*B]
    int B)
{
    // Packed per-n record: 16 floats = W[9], bias[3], c_rho, c_p, c_u, pad.
    __shared__ float sc[NN * 16];
    const int t = threadIdx.x;
    if (t < NN) {
        #pragma unroll
        for (int j = 0; j < 9; ++j) sc[t * 16 + j] = W[t * 9 + j];
        #pragma unroll
        for (int k = 0; k < 3; ++k) sc[t * 16 + 9 + k] = bias[t * 3 + k];
        sc[t * 16 + 12] = c_rho[t];
        sc[t * 16 + 13] = c_p[t];
        sc[t * 16 + 14] = c_u[t];
        sc[t * 16 + 15] = 0.0f;
    }
    __syncthreads();

    const int base = blockIdx.x * (BLK * RPT);

    // Load x for RPT rows (strided by BLK for coalescing); OOB rows -> x=0.
    float xr[RPT][3];
    int   rows[RPT];
    #pragma unroll
    for (int i = 0; i < RPT; ++i) {
        const int r = base + i * BLK + t;
        rows[i] = r;
        const bool ok = (r < B);
        xr[i][0] = ok ? x[r * 3 + 0] : 0.0f;
        xr[i][1] = ok ? x[r * 3 + 1] : 0.0f;
        xr[i][2] = ok ? x[r * 3 + 2] : 0.0f;
    }

    float acc[RPT][3];
    #pragma unroll
    for (int i = 0; i < RPT; ++i) {
        acc[i][0] = 0.0f; acc[i][1] = 0.0f; acc[i][2] = 0.0f;
    }

    const float4* scv = (const float4*)sc;
    #pragma unroll 4
    for (int n = 0; n < NN; ++n) {
        const float4 q0 = scv[n * 4 + 0];  // W0..W3
        const float4 q1 = scv[n * 4 + 1];  // W4..W7
        const float4 q2 = scv[n * 4 + 2];  // W8, b0, b1, b2
        const float4 q3 = scv[n * 4 + 3];  // c_rho, c_p, c_u, pad
        #pragma unroll
        for (int i = 0; i < RPT; ++i) {
            const float x0 = xr[i][0], x1 = xr[i][1], x2 = xr[i][2];
            // k=0: W[0..2], b0
            float h0 = fmaf(x2, q0.z, fmaf(x1, q0.y, fmaf(x0, q0.x, q2.y)));
            // k=1: W[3..5], b1
            float h1 = fmaf(x2, q1.y, fmaf(x1, q1.x, fmaf(x0, q0.w, q2.z)));
            // k=2: W[6..8], b2
            float h2 = fmaf(x2, q2.x, fmaf(x1, q1.w, fmaf(x0, q1.z, q2.w)));
            const float t0 = fast_tanh(h0);
            const float t1 = fast_tanh(h1);
            const float t2 = fast_tanh(h2);
            acc[i][0] = fmaf(t0, q3.x, acc[i][0]);
            acc[i][1] = fmaf(t1, q3.y, acc[i][1]);
            acc[i][2] = fmaf(t2, q3.z, acc[i][2]);
        }
    }

    #pragma unroll
    for (int i = 0; i < RPT; ++i) {
        const int r = rows[i];
        if (r < B) {
            out[r]         = acc[i][0];
            out[B + r]     = acc[i][1];
            out[2 * B + r] = acc[i][2];
        }
    }
}

extern "C" void kernel_launch(void* const* d_in, const int* in_sizes, int n_in,
                              void* d_out, int out_size, void* d_ws, size_t ws_size,
                              hipStream_t stream) {
    (void)d_ws; (void)ws_size; (void)n_in; (void)out_size;
    const float* x     = (const float*)d_in[0];
    const float* W     = (const float*)d_in[1];
    const float* bias  = (const float*)d_in[2];
    const float* c_rho = (const float*)d_in[3];
    const float* c_p   = (const float*)d_in[4];
    const float* c_u   = (const float*)d_in[5];
    float* out = (float*)d_out;

    const int B = in_sizes[0] / 3;
    const int rows_per_block = BLK * RPT;
    const int grid = (B + rows_per_block - 1) / rows_per_block;

    fused_tanh_heads<<<grid, BLK, 0, stream>>>(x, W, bias, c_rho, c_p, c_u, out, B);
}

// Round 4
// 113.274 us; speedup vs baseline: 1.1365x; 1.1365x over previous
//
#include <hip/hip_runtime.h>

// B=1e6 rows, N=64 heads, D=3.
// u[b,n,k] = tanh(x[b,:]·W[n,k,:] + bias[n,k]); out_k[b] = sum_n u[b,n,k]*c_k[n].
// d_out: [0..B)=rho, [B..2B)=p, [2B..3B)=u  (f32).
//
// tanh(h) = 1 - 2/(1+e^{2h}) = 1 - 2/(1+exp2(K*h)), K = 2*log2(e).
// K folded into W,b at LDS-fill. One rcp per row serves all 3 channels:
// inv_i = (prod_{j!=i} a_j) * rcp(prod_j a_j).

#define NN   64
#define RPT  2
#define BLK  256

typedef float f2 __attribute__((ext_vector_type(2)));

__device__ __forceinline__ f2 mk2(float a, float b) { f2 r; r.x = a; r.y = b; return r; }
__device__ __forceinline__ f2 pkfma(f2 a, f2 b, f2 c) { return __builtin_elementwise_fma(a, b, c); }

__device__ __forceinline__ float fexp2(float x) {
#if __has_builtin(__builtin_amdgcn_exp2f)
    return __builtin_amdgcn_exp2f(x);
#else
    return exp2f(x);
#endif
}
__device__ __forceinline__ float frcp(float x) {
#if __has_builtin(__builtin_amdgcn_rcpf)
    return __builtin_amdgcn_rcpf(x);
#else
    return 1.0f / x;
#endif
}

__global__ __launch_bounds__(BLK) void fused_tanh_heads(
    const float* __restrict__ x,     // [B,3]
    const float* __restrict__ W,     // [64,3,3]
    const float* __restrict__ bias,  // [64,3]
    const float* __restrict__ c_rho, // [64]
    const float* __restrict__ c_p,   // [64]
    const float* __restrict__ c_u,   // [64]
    float* __restrict__ out,         // [3*B]
    int B)
{
    // Per-n record: 32 floats = splatted {W'[9], b'[3], c_rho, c_p, c_u, pad}
    // as float2 pairs -> 8 x float4 broadcast reads per n.
    __shared__ float sc[NN * 32];
    const int t = threadIdx.x;
    if (t < NN) {
        const float K = 2.8853900817779268f;  // 2*log2(e)
        float* rec = &sc[t * 32];
        #pragma unroll
        for (int j = 0; j < 9; ++j) {
            const float w = W[t * 9 + j] * K;
            rec[2 * j] = w; rec[2 * j + 1] = w;
        }
        #pragma unroll
        for (int k = 0; k < 3; ++k) {
            const float bb = bias[t * 3 + k] * K;
            rec[18 + 2 * k] = bb; rec[19 + 2 * k] = bb;
        }
        const float cr = c_rho[t], cp = c_p[t], cu = c_u[t];
        rec[24] = cr; rec[25] = cr;
        rec[26] = cp; rec[27] = cp;
        rec[28] = cu; rec[29] = cu;
        rec[30] = 0.0f; rec[31] = 0.0f;
    }
    __syncthreads();

    const int r0 = blockIdx.x * (BLK * RPT) + t;
    const int r1 = r0 + BLK;
    const bool ok0 = (r0 < B), ok1 = (r1 < B);

    const f2 X0 = mk2(ok0 ? x[r0 * 3 + 0] : 0.0f, ok1 ? x[r1 * 3 + 0] : 0.0f);
    const f2 X1 = mk2(ok0 ? x[r0 * 3 + 1] : 0.0f, ok1 ? x[r1 * 3 + 1] : 0.0f);
    const f2 X2 = mk2(ok0 ? x[r0 * 3 + 2] : 0.0f, ok1 ? x[r1 * 3 + 2] : 0.0f);

    f2 acc0 = mk2(0.0f, 0.0f), acc1 = acc0, acc2 = acc0;
    const f2 neg2 = mk2(-2.0f, -2.0f), one2 = mk2(1.0f, 1.0f);

    const float4* q4 = (const float4*)sc;
    #pragma unroll 2
    for (int n = 0; n < NN; ++n) {
        const float4 Q0 = q4[n * 8 + 0];  // W00 W01
        const float4 Q1 = q4[n * 8 + 1];  // W02 W10
        const float4 Q2 = q4[n * 8 + 2];  // W11 W12
        const float4 Q3 = q4[n * 8 + 3];  // W20 W21
        const float4 Q4 = q4[n * 8 + 4];  // W22 B0
        const float4 Q5 = q4[n * 8 + 5];  // B1  B2
        const float4 Q6 = q4[n * 8 + 6];  // Crho Cp
        const float4 Q7 = q4[n * 8 + 7];  // Cu  pad

        // h'_k = K*(x·W[k] + b[k]) via packed fma over the row pair
        f2 h0 = pkfma(X2, mk2(Q1.x, Q1.y),
                 pkfma(X1, mk2(Q0.z, Q0.w),
                  pkfma(X0, mk2(Q0.x, Q0.y), mk2(Q4.z, Q4.w))));
        f2 h1 = pkfma(X2, mk2(Q2.z, Q2.w),
                 pkfma(X1, mk2(Q2.x, Q2.y),
                  pkfma(X0, mk2(Q1.z, Q1.w), mk2(Q5.x, Q5.y))));
        f2 h2 = pkfma(X2, mk2(Q4.x, Q4.y),
                 pkfma(X1, mk2(Q3.z, Q3.w),
                  pkfma(X0, mk2(Q3.x, Q3.y), mk2(Q5.z, Q5.w))));

        // a = exp2(h') + 1, per scalar value
        const float a00 = fexp2(h0.x) + 1.0f, a01 = fexp2(h0.y) + 1.0f;
        const float a10 = fexp2(h1.x) + 1.0f, a11 = fexp2(h1.y) + 1.0f;
        const float a20 = fexp2(h2.x) + 1.0f, a21 = fexp2(h2.y) + 1.0f;

        // one rcp per row for all 3 channels
        // row0
        const float m0  = a00 * a10;
        const float rA  = frcp(m0 * a20);
        const float i20 = m0 * rA;
        const float s0  = a20 * rA;
        const float i00 = a10 * s0;
        const float i10 = a00 * s0;
        // row1
        const float m1  = a01 * a11;
        const float rB  = frcp(m1 * a21);
        const float i21 = m1 * rB;
        const float s1  = a21 * rB;
        const float i01 = a11 * s1;
        const float i11 = a01 * s1;

        // tanh = 1 - 2*inv  (inline consts), then acc += tanh * c
        const f2 T0 = pkfma(neg2, mk2(i00, i01), one2);
        const f2 T1 = pkfma(neg2, mk2(i10, i11), one2);
        const f2 T2 = pkfma(neg2, mk2(i20, i21), one2);
        acc0 = pkfma(T0, mk2(Q6.x, Q6.y), acc0);
        acc1 = pkfma(T1, mk2(Q6.z, Q6.w), acc1);
        acc2 = pkfma(T2, mk2(Q7.x, Q7.y), acc2);
    }

    if (ok0) {
        out[r0]         = acc0.x;
        out[B + r0]     = acc1.x;
        out[2 * B + r0] = acc2.x;
    }
    if (ok1) {
        out[r1]         = acc0.y;
        out[B + r1]     = acc1.y;
        out[2 * B + r1] = acc2.y;
    }
}

extern "C" void kernel_launch(void* const* d_in, const int* in_sizes, int n_in,
                              void* d_out, int out_size, void* d_ws, size_t ws_size,
                              hipStream_t stream) {
    (void)d_ws; (void)ws_size; (void)n_in; (void)out_size;
    const float* x     = (const float*)d_in[0];
    const float* W     = (const float*)d_in[1];
    const float* bias  = (const float*)d_in[2];
    const float* c_rho = (const float*)d_in[3];
    const float* c_p   = (const float*)d_in[4];
    const float* c_u   = (const float*)d_in[5];
    float* out = (float*)d_out;

    const int B = in_sizes[0] / 3;
    const int rows_per_block = BLK * RPT;
    const int grid = (B + rows_per_block - 1) / rows_per_block;

    fused_tanh_heads<<<grid, BLK, 0, stream>>>(x, W, bias, c_rho, c_p, c_u, out, B);
}